// Round 4
// baseline (362.652 us; speedup 1.0000x reference)
//
#include <hip/hip_runtime.h>

#define T_DIM 16384
#define B_DIM 64
#define E_DIM 4096
#define NBLK  1024
#define CHUNK 16   // rows per block (T_DIM / NBLK)

typedef float f32x4 __attribute__((ext_vector_type(4)));

#define SCOPE_AGENT __HIP_MEMORY_SCOPE_AGENT

// ---------------------------------------------------------------------------
// Single fused kernel, CUB-style decoupled lookback (aggregate + prefix).
// flags[b]: 0 = nothing, 1 = aggA/aggB[b] valid (block aggregate),
//           2 = prefA/prefB[b] also valid (inclusive prefix of blocks 0..b).
// Publisher order: data (relaxed) then flag (release). Reader: flag (acquire)
// then data (relaxed). Aggregate and prefix live in SEPARATE arrays, so the
// 1->2 transition never overwrites a value a reader might be consuming.
// Lookback: 64-wide windows walking backward; short-circuits at the first
// flag==2 predecessor. Lanes poll their flag ONCE per retry, cache the value
// on success, and back off with s_sleep — fixes R3's L3 atomic storm.
// Compose (matches reference, state' = a*state + b):
//   inclusive step: B = a_j*B + b_j (old B); A = a_j*A.
//   compose(P earlier, S later) = (S.a*P.a, S.a*P.b + S.b).
// Deadlock-free: blocks only WAIT on flag>=1, set by every block before it
// waits on anything; all 1024 blocks co-resident (4 blocks/CU @ 256 thr).
// ---------------------------------------------------------------------------
__global__ __launch_bounds__(256, 4) void fused_kernel(
    const int*    __restrict__ indices,   // (T, B) int32
    const float*  __restrict__ params,    // (N, 2)
    const float*  __restrict__ M,         // (E,)
    float*        __restrict__ out,       // (T, E)
    float*        __restrict__ aggA,      // ws [NBLK]
    float*        __restrict__ aggB,      // ws [NBLK]
    float*        __restrict__ prefA,     // ws [NBLK]
    float*        __restrict__ prefB,     // ws [NBLK]
    unsigned int* __restrict__ flags)     // ws [NBLK], zeroed each replay
{
    __shared__ float sA[CHUNK], sB[CHUNK];
    __shared__ float sP[2];
    const int tid   = threadIdx.x;
    const int lane  = tid & 63;
    const int wave  = tid >> 6;          // 0..3
    const int blk   = blockIdx.x;
    const int tbase = blk * CHUNK;

    // ---------------- Phase 1: coeff sums for 16 rows (verified R2 code) ----
    {
        const float2* __restrict__ P2 = (const float2*)params;
        const int j0 = wave * 4;
        int i0 = indices[((tbase + j0 + 0) << 6) + lane];
        int i1 = indices[((tbase + j0 + 1) << 6) + lane];
        int i2 = indices[((tbase + j0 + 2) << 6) + lane];
        int i3 = indices[((tbase + j0 + 3) << 6) + lane];
        float2 p0 = P2[i0], p1 = P2[i1], p2 = P2[i2], p3 = P2[i3];
        float a0 = p0.x, b0 = p0.y, a1 = p1.x, b1 = p1.y;
        float a2 = p2.x, b2 = p2.y, a3 = p3.x, b3 = p3.y;
        #pragma unroll
        for (int off = 32; off >= 1; off >>= 1) {
            a0 += __shfl_down(a0, off, 64);  b0 += __shfl_down(b0, off, 64);
            a1 += __shfl_down(a1, off, 64);  b1 += __shfl_down(b1, off, 64);
            a2 += __shfl_down(a2, off, 64);  b2 += __shfl_down(b2, off, 64);
            a3 += __shfl_down(a3, off, 64);  b3 += __shfl_down(b3, off, 64);
        }
        if (lane == 0) {
            sA[j0+0] = a0; sB[j0+0] = b0;
            sA[j0+1] = a1; sB[j0+1] = b1;
            sA[j0+2] = a2; sB[j0+2] = b2;
            sA[j0+3] = a3; sB[j0+3] = b3;
        }
    }
    __syncthreads();

    // local inclusive scan + publish block aggregate (flag = 1, release)
    float own_a = 0.0f, own_b = 0.0f;    // meaningful on tid 0 only
    if (tid == 0) {
        float a = 1.0f, b = 0.0f;
        #pragma unroll
        for (int j = 0; j < CHUNK; ++j) {
            float aj = sA[j], bj = sB[j];
            b = aj * b + bj;             // uses old b only
            a = aj * a;
            sA[j] = a; sB[j] = b;
        }
        own_a = a; own_b = b;
        __hip_atomic_store(&aggA[blk], a, __ATOMIC_RELAXED, SCOPE_AGENT);
        __hip_atomic_store(&aggB[blk], b, __ATOMIC_RELAXED, SCOPE_AGENT);
        __hip_atomic_store(&flags[blk], 1u, __ATOMIC_RELEASE, SCOPE_AGENT);
    }

    // M into registers: 16 KB broadcast read, overlaps the lookback
    const f32x4* __restrict__ M4 = (const f32x4*)M;
    f32x4 m0 = M4[tid], m1 = M4[tid + 256], m2 = M4[tid + 512], m3 = M4[tid + 768];

    // ---------------- Phase 2: decoupled lookback (wave 0 only) -------------
    if (wave == 0) {
        float Xa = 1.0f, Xb = 0.0f;      // exclusive prefix for this block
        float ACCa = 1.0f, ACCb = 0.0f;  // composition of blocks (widx..blk-1]
        int  widx = blk - 1;
        bool done = (widx < 0);
        while (!done) {
            const int  base = widx - 63;         // lane l <-> block base+l
            const int  idx  = base + lane;
            const bool act  = idx >= 0;
            float a = 1.0f, b = 0.0f;
            unsigned fl = 0u;
            bool have = !act;
            for (;;) {                            // poll-once-per-retry + cache
                if (!have) {
                    fl = __hip_atomic_load(&flags[idx], __ATOMIC_ACQUIRE, SCOPE_AGENT);
                    if (fl != 0u) {
                        if (fl == 2u) {
                            a = __hip_atomic_load(&prefA[idx], __ATOMIC_RELAXED, SCOPE_AGENT);
                            b = __hip_atomic_load(&prefB[idx], __ATOMIC_RELAXED, SCOPE_AGENT);
                        } else {
                            a = __hip_atomic_load(&aggA[idx], __ATOMIC_RELAXED, SCOPE_AGENT);
                            b = __hip_atomic_load(&aggB[idx], __ATOMIC_RELAXED, SCOPE_AGENT);
                        }
                        have = true;
                    }
                }
                if (__all(have)) break;
                __builtin_amdgcn_s_sleep(2);
            }
            const unsigned long long m2 = __ballot(act && (fl == 2u));
            if (m2 != 0ull) {
                // closest predecessor with a full inclusive prefix
                const int L = 63 - __clzll(m2);
                float Pa = __shfl(a, L, 64);
                float Pb = __shfl(b, L, 64);
                for (int s = L + 1; s < 64; ++s) {   // compose later aggregates
                    const float sa = __shfl(a, s, 64);
                    const float sb = __shfl(b, s, 64);
                    Pb = sa * Pb + sb;               // uses OLD Pb; sa later
                    Pa = sa * Pa;
                }
                Xa = ACCa * Pa;                      // compose(Pw earlier, ACC later)
                Xb = ACCa * Pb + ACCb;
                done = true;
            } else {
                // whole window is aggregates: 6-step inclusive shuffle scan
                float ia = a, ib = b;
                #pragma unroll
                for (int off = 1; off < 64; off <<= 1) {
                    const float pa = __shfl_up(ia, off, 64);
                    const float pb = __shfl_up(ib, off, 64);
                    if (lane >= off) {
                        const float nb = ia * pb + ib;  // uses OLD ia
                        ia = ia * pa;
                        ib = nb;
                    }
                }
                const float Sa = __shfl(ia, 63, 64);
                const float Sb = __shfl(ib, 63, 64);
                const float nb = ACCa * Sb + ACCb;   // compose(S earlier, ACC later)
                ACCa = ACCa * Sa;
                ACCb = nb;
                widx = base - 1;
                if (widx < 0) { Xa = ACCa; Xb = ACCb; done = true; }
            }
        }
        if (lane == 0) {
            sP[0] = Xa; sP[1] = Xb;
            // publish inclusive prefix (flag = 2, release) for later blocks
            const float inc_a = own_a * Xa;
            const float inc_b = own_a * Xb + own_b;
            __hip_atomic_store(&prefA[blk], inc_a, __ATOMIC_RELAXED, SCOPE_AGENT);
            __hip_atomic_store(&prefB[blk], inc_b, __ATOMIC_RELAXED, SCOPE_AGENT);
            __hip_atomic_store(&flags[blk], 2u, __ATOMIC_RELEASE, SCOPE_AGENT);
        }
    }
    __syncthreads();

    // ---------------- Phase 3: apply prefix, stream 16 output rows ----------
    const float Pa = sP[0], Pb = sP[1];
    #pragma unroll
    for (int j = 0; j < CHUNK; ++j) {
        const float la = sA[j], lb = sB[j];
        const float At = la * Pa;
        const float Bt = la * Pb + lb;
        f32x4* __restrict__ O4 = (f32x4*)(out + (size_t)(tbase + j) * E_DIM);
        f32x4 r;
        r = At * m0 + Bt;  __builtin_nontemporal_store(r, &O4[tid      ]);
        r = At * m1 + Bt;  __builtin_nontemporal_store(r, &O4[tid + 256]);
        r = At * m2 + Bt;  __builtin_nontemporal_store(r, &O4[tid + 512]);
        r = At * m3 + Bt;  __builtin_nontemporal_store(r, &O4[tid + 768]);
    }
}

extern "C" void kernel_launch(void* const* d_in, const int* in_sizes, int n_in,
                              void* d_out, int out_size, void* d_ws, size_t ws_size,
                              hipStream_t stream) {
    const int*   indices = (const int*)d_in[0];     // (T, B) int32 on device
    const float* M_prev  = (const float*)d_in[1];   // (E,)
    const float* params  = (const float*)d_in[2];   // (N, 2)
    float* out = (float*)d_out;

    float*        aggA  = (float*)d_ws;                 // [NBLK]
    float*        aggB  = aggA + NBLK;                  // [NBLK]
    float*        prefA = aggB + NBLK;                  // [NBLK]
    float*        prefB = prefA + NBLK;                 // [NBLK]
    unsigned int* flags = (unsigned int*)(prefB + NBLK);// [NBLK]

    // re-zero flags every replay (ws is poisoned by the harness each iteration)
    hipMemsetAsync(flags, 0, NBLK * sizeof(unsigned int), stream);

    fused_kernel<<<NBLK, 256, 0, stream>>>(indices, params, M_prev, out,
                                           aggA, aggB, prefA, prefB, flags);
}

// Round 5
// 289.511 us; speedup vs baseline: 1.2526x; 1.2526x over previous
//
#include <hip/hip_runtime.h>

#define T_DIM 16384
#define B_DIM 64
#define E_DIM 4096
#define NBLK  1024
#define CHUNK 16   // rows per block (T_DIM / NBLK)

typedef float f32x4 __attribute__((ext_vector_type(4)));

// ---------------------------------------------------------------------------
// K1: per block of 16 rows (= 1024 indices = 4KB):
//   each thread: one int4 load (coalesced), 4 ILP float2 gathers, local sum,
//   4-step shuffle tree within the 16-lane group owning one row.
//   Then thread 0: serial inclusive scan of the 16 (a,b) pairs; write per-row
//   local scans (lab) and the block aggregate (agg).
// Compose (matches reference, state' = a*state + b):
//   inclusive step: B = a_j*B + b_j (old B); A = a_j*A.
// ---------------------------------------------------------------------------
__global__ __launch_bounds__(256) void coeff_scan_kernel(
    const int*   __restrict__ indices,   // (T, B) int32
    const float* __restrict__ params,    // (N, 2)
    float2*      __restrict__ lab,       // [T] local inclusive scans
    float2*      __restrict__ agg)       // [NBLK] block aggregates
{
    __shared__ float sA[CHUNK], sB[CHUNK];
    const int tid   = threadIdx.x;
    const int blk   = blockIdx.x;
    const int tbase = blk * CHUNK;
    const float2* __restrict__ P2 = (const float2*)params;

    // thread tid owns indices [tid*4 .. tid*4+3] of this block's 1024;
    // row of these 4 = tid >> 4 (16 threads per row, contiguous lanes).
    const int4* __restrict__ I4 = (const int4*)(indices + tbase * B_DIM);
    const int4 iv = I4[tid];
    float2 g0 = P2[iv.x], g1 = P2[iv.y], g2 = P2[iv.z], g3 = P2[iv.w];
    float a = (g0.x + g1.x) + (g2.x + g3.x);
    float b = (g0.y + g1.y) + (g2.y + g3.y);
    // tree-reduce within the 16-lane group (lanes with group-pos >= 8 go stale
    // after step 1 but are never consumed — standard tree)
    #pragma unroll
    for (int off = 8; off >= 1; off >>= 1) {
        a += __shfl_down(a, off, 64);
        b += __shfl_down(b, off, 64);
    }
    if ((tid & 15) == 0) { sA[tid >> 4] = a; sB[tid >> 4] = b; }
    __syncthreads();

    if (tid == 0) {
        float A = 1.0f, B = 0.0f;
        #pragma unroll
        for (int j = 0; j < CHUNK; ++j) {
            float aj = sA[j], bj = sB[j];
            B = aj * B + bj;             // uses old B only
            A = aj * A;
            sA[j] = A; sB[j] = B;
        }
        agg[blk] = make_float2(A, B);
    }
    __syncthreads();
    if (tid < CHUNK) lab[tbase + tid] = make_float2(sA[tid], sB[tid]);
}

// ---------------------------------------------------------------------------
// K2+K3 fused: per block of 16 rows:
//   wave 0 redundantly computes this block's exclusive prefix by scanning
//   agg[0..blk-1] in 64-wide windows (order-preserving masked Hillis-Steele,
//   compose window totals forward); waves 1-3 meanwhile preload M into regs.
//   Then all 256 threads stream 16 output rows (nontemporal float4 stores).
// compose(E earlier, L later) = (L.a*E.a, L.a*E.b + L.b); identity (1,0).
// agg[] is complete before this kernel launches (stream order) — no flags.
// ---------------------------------------------------------------------------
__global__ __launch_bounds__(256) void out_kernel(
    const float2* __restrict__ lab,
    const float2* __restrict__ agg,
    const float*  __restrict__ M,
    float*        __restrict__ out)
{
    __shared__ float2 s[CHUNK];
    __shared__ float sP[2];
    const int tid   = threadIdx.x;
    const int lane  = tid & 63;
    const int blk   = blockIdx.x;
    const int tbase = blk * CHUNK;
    if (tid < CHUNK) s[tid] = lab[tbase + tid];

    const f32x4* __restrict__ M4 = (const f32x4*)M;
    f32x4 m0 = M4[tid], m1 = M4[tid + 256], m2 = M4[tid + 512], m3 = M4[tid + 768];

    if (tid < 64) {
        float Xa = 1.0f, Xb = 0.0f;          // exclusive prefix of this block
        const int nwin = (blk + 63) >> 6;    // windows covering agg[0..blk-1]
        for (int w = 0; w < nwin; ++w) {
            const int idx = (w << 6) + lane;
            float a = 1.0f, b = 0.0f;        // identity padding at the tail
            if (idx < blk) { float2 g = agg[idx]; a = g.x; b = g.y; }
            // order-preserving inclusive shuffle scan (verified R2 K2 pattern)
            #pragma unroll
            for (int off = 1; off < 64; off <<= 1) {
                const float pa = __shfl_up(a, off, 64);
                const float pb = __shfl_up(b, off, 64);
                if (lane >= off) {
                    const float nb = a * pb + b;   // uses OLD a
                    a = a * pa;
                    b = nb;
                }
            }
            const float Sa = __shfl(a, 63, 64);    // window total
            const float Sb = __shfl(b, 63, 64);
            Xb = Sa * Xb + Sb;                     // compose(X earlier, S later)
            Xa = Sa * Xa;
        }
        if (lane == 0) { sP[0] = Xa; sP[1] = Xb; }
    }
    __syncthreads();

    const float Pa = sP[0], Pb = sP[1];
    #pragma unroll
    for (int j = 0; j < CHUNK; ++j) {
        const float la = s[j].x, lb = s[j].y;
        const float At = la * Pa;
        const float Bt = la * Pb + lb;
        f32x4* __restrict__ O4 = (f32x4*)(out + (size_t)(tbase + j) * E_DIM);
        f32x4 r;
        r = At * m0 + Bt;  __builtin_nontemporal_store(r, &O4[tid      ]);
        r = At * m1 + Bt;  __builtin_nontemporal_store(r, &O4[tid + 256]);
        r = At * m2 + Bt;  __builtin_nontemporal_store(r, &O4[tid + 512]);
        r = At * m3 + Bt;  __builtin_nontemporal_store(r, &O4[tid + 768]);
    }
}

extern "C" void kernel_launch(void* const* d_in, const int* in_sizes, int n_in,
                              void* d_out, int out_size, void* d_ws, size_t ws_size,
                              hipStream_t stream) {
    const int*   indices = (const int*)d_in[0];     // (T, B) int32 on device
    const float* M_prev  = (const float*)d_in[1];   // (E,)
    const float* params  = (const float*)d_in[2];   // (N, 2)
    float* out = (float*)d_out;

    float2* lab = (float2*)d_ws;                    // [T_DIM]
    float2* agg = lab + T_DIM;                      // [NBLK]

    coeff_scan_kernel<<<NBLK, 256, 0, stream>>>(indices, params, lab, agg);
    out_kernel<<<NBLK, 256, 0, stream>>>(lab, agg, M_prev, out);
}